// Round 1
// baseline (1181.832 us; speedup 1.0000x reference)
//
#include <hip/hip_runtime.h>

#define ALPHA 0.9f
#define BETA  0.85f
#define TSIM  50
#define BATCH 128
#define N0    1024
#define N1    2048
#define N2    2048
#define N3    512

// ---------------------------------------------------------------------------
// Generic fp32 tiled GEMM: C(M,N) = A(M,K) @ B(K,N), all row-major.
// 64x64 output tile per block, 256 threads, 4x4 micro-tile per thread,
// K staged in LDS 16 at a time. Requires M%64==0, N%64==0, K%16==0.
// ---------------------------------------------------------------------------
__global__ __launch_bounds__(256) void gemm_f32(const float* __restrict__ A,
                                                const float* __restrict__ B,
                                                float* __restrict__ C,
                                                int M, int N, int K) {
    __shared__ float As[16][65];  // +1 pad breaks 4-way bank conflict on write
    __shared__ float Bs[16][68];  // +4 pad keeps float4 alignment, shifts banks

    const int tid = threadIdx.x;
    const int tx  = tid % 16;          // column group
    const int ty  = tid / 16;          // row group
    const int bx  = blockIdx.x;        // N tile
    const int by  = blockIdx.y;        // M tile

    float acc[4][4] = {};

    const int ar = tid / 4;            // A tile row 0..63
    const int ak = (tid % 4) * 4;      // A tile k   0,4,8,12
    const int br = tid / 16;           // B tile k   0..15
    const int bc = (tid % 16) * 4;     // B tile col 0..60

    for (int k0 = 0; k0 < K; k0 += 16) {
        float4 av = *(const float4*)&A[(size_t)(by * 64 + ar) * K + k0 + ak];
        As[ak + 0][ar] = av.x;
        As[ak + 1][ar] = av.y;
        As[ak + 2][ar] = av.z;
        As[ak + 3][ar] = av.w;
        float4 bv = *(const float4*)&B[(size_t)(k0 + br) * N + bx * 64 + bc];
        *(float4*)&Bs[br][bc] = bv;
        __syncthreads();

#pragma unroll
        for (int kk = 0; kk < 16; ++kk) {
            float a0 = As[kk][ty * 4 + 0];
            float a1 = As[kk][ty * 4 + 1];
            float a2 = As[kk][ty * 4 + 2];
            float a3 = As[kk][ty * 4 + 3];
            float b0 = Bs[kk][tx * 4 + 0];
            float b1 = Bs[kk][tx * 4 + 1];
            float b2 = Bs[kk][tx * 4 + 2];
            float b3 = Bs[kk][tx * 4 + 3];
            acc[0][0] += a0 * b0; acc[0][1] += a0 * b1; acc[0][2] += a0 * b2; acc[0][3] += a0 * b3;
            acc[1][0] += a1 * b0; acc[1][1] += a1 * b1; acc[1][2] += a1 * b2; acc[1][3] += a1 * b3;
            acc[2][0] += a2 * b0; acc[2][1] += a2 * b1; acc[2][2] += a2 * b2; acc[2][3] += a2 * b3;
            acc[3][0] += a3 * b0; acc[3][1] += a3 * b1; acc[3][2] += a3 * b2; acc[3][3] += a3 * b3;
        }
        __syncthreads();
    }

#pragma unroll
    for (int i = 0; i < 4; ++i) {
        float4 v = make_float4(acc[i][0], acc[i][1], acc[i][2], acc[i][3]);
        *(float4*)&C[(size_t)(by * 64 + ty * 4 + i) * N + bx * 64 + tx * 4] = v;
    }
}

// ---------------------------------------------------------------------------
// Layer-0 scan: purely elementwise in H0 (drive is constant over time).
// m = BETA*m + h0 ; spike = (m-1) > 0 ; hard reset on spike.
// Emits the full spike raster S0[t][b][j] as fp32 {0,1}.
// ---------------------------------------------------------------------------
__global__ __launch_bounds__(256) void scan_l0(const float* __restrict__ H0,
                                               float* __restrict__ S0) {
    const int idx = blockIdx.x * 256 + threadIdx.x;   // over BATCH*N1
    const float h = H0[idx];
    float m = 0.f;
#pragma unroll
    for (int t = 0; t < TSIM; ++t) {
        m = BETA * m + h;              // s = h for layer 0
        const float mthr = m - 1.f;
        const float spk = (mthr > 0.f) ? 1.f : 0.f;
        S0[(size_t)t * (BATCH * N1) + idx] = spk;
        if (mthr > 0.f) m = 0.f;       // hard reset
    }
}

// ---------------------------------------------------------------------------
// Layer-1 scan: s = ALPHA*s + h1[t] ; m = BETA*m + s ; spike; reset.
// Reads H1 raster, writes S1 raster.
// ---------------------------------------------------------------------------
__global__ __launch_bounds__(256) void scan_l1(const float* __restrict__ H1,
                                               float* __restrict__ S1) {
    const int idx = blockIdx.x * 256 + threadIdx.x;   // over BATCH*N2
    float s = 0.f, m = 0.f;
#pragma unroll
    for (int t = 0; t < TSIM; ++t) {
        const float h = H1[(size_t)t * (BATCH * N2) + idx];
        s = ALPHA * s + h;
        m = BETA * m + s;
        const float mthr = m - 1.f;
        S1[(size_t)t * (BATCH * N2) + idx] = (mthr > 0.f) ? 1.f : 0.f;
        if (mthr > 0.f) m = 0.f;
    }
}

// ---------------------------------------------------------------------------
// Layer-2 scan: output layer, never resets. Emit final membrane.
// ---------------------------------------------------------------------------
__global__ __launch_bounds__(256) void scan_l2(const float* __restrict__ H2,
                                               float* __restrict__ out) {
    const int idx = blockIdx.x * 256 + threadIdx.x;   // over BATCH*N3
    float s = 0.f, m = 0.f;
#pragma unroll
    for (int t = 0; t < TSIM; ++t) {
        const float h = H2[(size_t)t * (BATCH * N3) + idx];
        s = ALPHA * s + h;
        m = BETA * m + s;
    }
    out[idx] = m;
}

extern "C" void kernel_launch(void* const* d_in, const int* in_sizes, int n_in,
                              void* d_out, int out_size, void* d_ws, size_t ws_size,
                              hipStream_t stream) {
    const float* inputs = (const float*)d_in[0];   // (128, 1024)
    const float* W0     = (const float*)d_in[1];   // (1024, 2048)
    const float* W1     = (const float*)d_in[2];   // (2048, 2048)
    const float* W2     = (const float*)d_in[3];   // (2048, 512)
    float* out = (float*)d_out;                    // (128, 512)

    float* ws = (float*)d_ws;
    float* H0 = ws;                                // BATCH*N1            (1 MB)
    float* P1 = H0 + (size_t)BATCH * N1;           // TSIM*BATCH*N1       (52 MB)  S0, then S1
    float* P2 = P1 + (size_t)TSIM * BATCH * N1;    // TSIM*BATCH*N2       (52 MB)  H1, then H2

    // 1. H0 = inputs @ W0   (128 x 1024 x 2048)
    gemm_f32<<<dim3(N1 / 64, BATCH / 64), 256, 0, stream>>>(inputs, W0, H0, BATCH, N1, N0);

    // 2. layer-0 scan -> full spike raster S0 (50 x 128 x 2048) in P1
    scan_l0<<<(BATCH * N1) / 256, 256, 0, stream>>>(H0, P1);

    // 3. H1 = S0 @ W1   (6400 x 2048 x 2048) -> P2
    gemm_f32<<<dim3(N2 / 64, (TSIM * BATCH) / 64), 256, 0, stream>>>(P1, W1, P2,
                                                                     TSIM * BATCH, N2, N1);

    // 4. layer-1 scan -> spike raster S1 in P1 (overwrites S0, already consumed)
    scan_l1<<<(BATCH * N2) / 256, 256, 0, stream>>>(P2, P1);

    // 5. H2 = S1 @ W2   (6400 x 2048 x 512) -> P2 (overwrites H1, already consumed)
    gemm_f32<<<dim3(N3 / 64, (TSIM * BATCH) / 64), 256, 0, stream>>>(P1, W2, P2,
                                                                     TSIM * BATCH, N3, N2);

    // 6. layer-2 scan -> final membrane (128 x 512)
    scan_l2<<<(BATCH * N3) / 256, 256, 0, stream>>>(P2, out);
}

// Round 2
// 384.809 us; speedup vs baseline: 3.0712x; 3.0712x over previous
//
#include <hip/hip_runtime.h>
#include <hip/hip_bf16.h>

#define ALPHA 0.9f
#define BETA  0.85f
#define TSIM  50
#define BATCH 128
#define N0    1024
#define N1    2048
#define N2    2048
#define N3    512

typedef __attribute__((ext_vector_type(8))) short bf16x8;
typedef __attribute__((ext_vector_type(4))) float f32x4;

#define GLOBAL_AS __attribute__((address_space(1)))
#define LDS_AS    __attribute__((address_space(3)))

// ---------------------------------------------------------------------------
// fp32 tiled GEMM (layer 0 only: 128 x 1024 x 2048 — tiny, keep exact fp32).
// ---------------------------------------------------------------------------
__global__ __launch_bounds__(256) void gemm_f32(const float* __restrict__ A,
                                                const float* __restrict__ B,
                                                float* __restrict__ C,
                                                int M, int N, int K) {
    __shared__ float As[16][65];
    __shared__ float Bs[16][68];

    const int tid = threadIdx.x;
    const int tx  = tid % 16;
    const int ty  = tid / 16;
    const int bx  = blockIdx.x;
    const int by  = blockIdx.y;

    float acc[4][4] = {};

    const int ar = tid / 4;
    const int ak = (tid % 4) * 4;
    const int br = tid / 16;
    const int bc = (tid % 16) * 4;

    for (int k0 = 0; k0 < K; k0 += 16) {
        float4 av = *(const float4*)&A[(size_t)(by * 64 + ar) * K + k0 + ak];
        As[ak + 0][ar] = av.x;
        As[ak + 1][ar] = av.y;
        As[ak + 2][ar] = av.z;
        As[ak + 3][ar] = av.w;
        float4 bv = *(const float4*)&B[(size_t)(k0 + br) * N + bx * 64 + bc];
        *(float4*)&Bs[br][bc] = bv;
        __syncthreads();

#pragma unroll
        for (int kk = 0; kk < 16; ++kk) {
            float a0 = As[kk][ty * 4 + 0];
            float a1 = As[kk][ty * 4 + 1];
            float a2 = As[kk][ty * 4 + 2];
            float a3 = As[kk][ty * 4 + 3];
            float b0 = Bs[kk][tx * 4 + 0];
            float b1 = Bs[kk][tx * 4 + 1];
            float b2 = Bs[kk][tx * 4 + 2];
            float b3 = Bs[kk][tx * 4 + 3];
            acc[0][0] += a0 * b0; acc[0][1] += a0 * b1; acc[0][2] += a0 * b2; acc[0][3] += a0 * b3;
            acc[1][0] += a1 * b0; acc[1][1] += a1 * b1; acc[1][2] += a1 * b2; acc[1][3] += a1 * b3;
            acc[2][0] += a2 * b0; acc[2][1] += a2 * b1; acc[2][2] += a2 * b2; acc[2][3] += a2 * b3;
            acc[3][0] += a3 * b0; acc[3][1] += a3 * b1; acc[3][2] += a3 * b2; acc[3][3] += a3 * b3;
        }
        __syncthreads();
    }

#pragma unroll
    for (int i = 0; i < 4; ++i) {
        float4 v = make_float4(acc[i][0], acc[i][1], acc[i][2], acc[i][3]);
        *(float4*)&C[(size_t)(by * 64 + ty * 4 + i) * N + bx * 64 + tx * 4] = v;
    }
}

// ---------------------------------------------------------------------------
// Split fp32 weight W(K,N) into transposed bf16 pair Th,Tl (N,K):
//   Th[n][k] = bf16(W[k][n]);  Tl[n][k] = bf16(W[k][n] - f32(Th[n][k]))
// 32x32 LDS-tiled transpose, 256 threads.
// ---------------------------------------------------------------------------
__global__ __launch_bounds__(256) void split_transpose(const float* __restrict__ W,
                                                       __hip_bfloat16* __restrict__ Th,
                                                       __hip_bfloat16* __restrict__ Tl,
                                                       int K, int N) {
    __shared__ float tile[32][33];
    const int tx = threadIdx.x % 32;
    const int ty = threadIdx.x / 32;            // 0..7
    const int k0 = blockIdx.y * 32;
    const int n0 = blockIdx.x * 32;

#pragma unroll
    for (int i = 0; i < 4; ++i)
        tile[ty + i * 8][tx] = W[(size_t)(k0 + ty + i * 8) * N + n0 + tx];
    __syncthreads();

#pragma unroll
    for (int i = 0; i < 4; ++i) {
        const float w = tile[tx][ty + i * 8];   // = W[k0+tx][n0+ty+i*8]
        const __hip_bfloat16 hi = __float2bfloat16(w);
        const float lo = w - __bfloat162float(hi);
        const size_t o = (size_t)(n0 + ty + i * 8) * K + k0 + tx;
        Th[o] = hi;
        Tl[o] = __float2bfloat16(lo);
    }
}

// ---------------------------------------------------------------------------
// MFMA GEMM: C(M,N) = A(M,K) @ (Bh + Bl)^T where Bh,Bl are (N,K) bf16,
// A is (M,K) bf16. fp32 accumulate. BM=128, BK=32, BN template.
// 256 threads = 4 waves in a WGM x WGN grid; per-wave WMT x WNT 16x16 tiles.
// m97-style: global_load_lds width=16 staging, ds_read_b128 fragments.
// ---------------------------------------------------------------------------
template <int BN, int WGM, int WGN, int WMT, int WNT>
__global__ __launch_bounds__(256) void gemm_bf16_split(const __hip_bfloat16* __restrict__ A,
                                                       const __hip_bfloat16* __restrict__ Bh,
                                                       const __hip_bfloat16* __restrict__ Bl,
                                                       float* __restrict__ C,
                                                       int M, int N, int K) {
    constexpr int BM = 128;
    constexpr int BK = 32;
    constexpr int NA = (BM * BK) / (256 * 8);   // A staging issues per thread (=2)
    constexpr int NB = (BN * BK) / (256 * 8);   // B staging issues per thread

    __shared__ alignas(16) __hip_bfloat16 As[BM * BK];
    __shared__ alignas(16) __hip_bfloat16 Bhs[BN * BK];
    __shared__ alignas(16) __hip_bfloat16 Bls[BN * BK];

    const int tid  = threadIdx.x;
    const int wave = tid >> 6;
    const int lane = tid & 63;
    const int quad = lane >> 4;
    const int l16  = lane & 15;

    const int m0 = blockIdx.y * BM;
    const int n0 = blockIdx.x * BN;

    const int wm = (wave % WGM) * (WMT * 16);
    const int wn = (wave / WGM) * (WNT * 16);

    f32x4 acc[WMT][WNT] = {};

    // staging descriptors: chunk c -> LDS bytes [c*16, c*16+16), global row c/4, colgroup c%4
    const __hip_bfloat16* agp[NA];
    int aoff[NA];
#pragma unroll
    for (int i = 0; i < NA; ++i) {
        const int c = i * 256 + tid;
        agp[i]  = A + (size_t)(m0 + (c >> 2)) * K + (c & 3) * 8;
        aoff[i] = c * 8;
    }
    const __hip_bfloat16 *bhgp[NB], *blgp[NB];
    int boff[NB];
#pragma unroll
    for (int i = 0; i < NB; ++i) {
        const int c = i * 256 + tid;
        bhgp[i] = Bh + (size_t)(n0 + (c >> 2)) * K + (c & 3) * 8;
        blgp[i] = Bl + (size_t)(n0 + (c >> 2)) * K + (c & 3) * 8;
        boff[i] = c * 8;
    }

    for (int k0 = 0; k0 < K; k0 += BK) {
#pragma unroll
        for (int i = 0; i < NA; ++i)
            __builtin_amdgcn_global_load_lds((const GLOBAL_AS void*)(agp[i] + k0),
                                             (LDS_AS void*)&As[aoff[i]], 16, 0, 0);
#pragma unroll
        for (int i = 0; i < NB; ++i) {
            __builtin_amdgcn_global_load_lds((const GLOBAL_AS void*)(bhgp[i] + k0),
                                             (LDS_AS void*)&Bhs[boff[i]], 16, 0, 0);
            __builtin_amdgcn_global_load_lds((const GLOBAL_AS void*)(blgp[i] + k0),
                                             (LDS_AS void*)&Bls[boff[i]], 16, 0, 0);
        }
        __syncthreads();

        bf16x8 af[WMT], bhf[WNT], blf[WNT];
#pragma unroll
        for (int i = 0; i < WMT; ++i)
            af[i] = *(const bf16x8*)&As[(wm + i * 16 + l16) * BK + quad * 8];
#pragma unroll
        for (int j = 0; j < WNT; ++j) {
            bhf[j] = *(const bf16x8*)&Bhs[(wn + j * 16 + l16) * BK + quad * 8];
            blf[j] = *(const bf16x8*)&Bls[(wn + j * 16 + l16) * BK + quad * 8];
        }
#pragma unroll
        for (int i = 0; i < WMT; ++i)
#pragma unroll
            for (int j = 0; j < WNT; ++j) {
                acc[i][j] = __builtin_amdgcn_mfma_f32_16x16x32_bf16(af[i], bhf[j], acc[i][j], 0, 0, 0);
                acc[i][j] = __builtin_amdgcn_mfma_f32_16x16x32_bf16(af[i], blf[j], acc[i][j], 0, 0, 0);
            }
        __syncthreads();
    }

    // C/D layout: col = lane&15, row = quad*4 + reg
#pragma unroll
    for (int i = 0; i < WMT; ++i)
#pragma unroll
        for (int j = 0; j < WNT; ++j)
#pragma unroll
            for (int r = 0; r < 4; ++r)
                C[(size_t)(m0 + wm + i * 16 + quad * 4 + r) * N + n0 + wn + j * 16 + l16] =
                    acc[i][j][r];
}

// ---------------------------------------------------------------------------
// Layer-0 scan: drive constant over time; emit bf16 spike raster.
// ---------------------------------------------------------------------------
__global__ __launch_bounds__(256) void scan_l0(const float* __restrict__ H0,
                                               __hip_bfloat16* __restrict__ S0) {
    const int idx = blockIdx.x * 256 + threadIdx.x;
    const float h = H0[idx];
    float m = 0.f;
#pragma unroll
    for (int t = 0; t < TSIM; ++t) {
        m = BETA * m + h;
        const float mthr = m - 1.f;
        S0[(size_t)t * (BATCH * N1) + idx] = __float2bfloat16(mthr > 0.f ? 1.f : 0.f);
        if (mthr > 0.f) m = 0.f;
    }
}

// ---------------------------------------------------------------------------
// Layer-1 scan: reads fp32 drive raster, emits bf16 spike raster.
// ---------------------------------------------------------------------------
__global__ __launch_bounds__(256) void scan_l1(const float* __restrict__ H1,
                                               __hip_bfloat16* __restrict__ S1) {
    const int idx = blockIdx.x * 256 + threadIdx.x;
    float s = 0.f, m = 0.f;
#pragma unroll
    for (int t = 0; t < TSIM; ++t) {
        const float h = H1[(size_t)t * (BATCH * N2) + idx];
        s = ALPHA * s + h;
        m = BETA * m + s;
        const float mthr = m - 1.f;
        S1[(size_t)t * (BATCH * N2) + idx] = __float2bfloat16(mthr > 0.f ? 1.f : 0.f);
        if (mthr > 0.f) m = 0.f;
    }
}

// ---------------------------------------------------------------------------
// Layer-2 scan: output layer, no reset; emit final membrane.
// ---------------------------------------------------------------------------
__global__ __launch_bounds__(256) void scan_l2(const float* __restrict__ H2,
                                               float* __restrict__ out) {
    const int idx = blockIdx.x * 256 + threadIdx.x;
    float s = 0.f, m = 0.f;
#pragma unroll
    for (int t = 0; t < TSIM; ++t) {
        const float h = H2[(size_t)t * (BATCH * N3) + idx];
        s = ALPHA * s + h;
        m = BETA * m + s;
    }
    out[idx] = m;
}

extern "C" void kernel_launch(void* const* d_in, const int* in_sizes, int n_in,
                              void* d_out, int out_size, void* d_ws, size_t ws_size,
                              hipStream_t stream) {
    const float* inputs = (const float*)d_in[0];   // (128, 1024)
    const float* W0     = (const float*)d_in[1];   // (1024, 2048)
    const float* W1     = (const float*)d_in[2];   // (2048, 2048)
    const float* W2     = (const float*)d_in[3];   // (2048, 512)
    float* out = (float*)d_out;                    // (128, 512)

    // workspace layout (bytes)
    char* ws = (char*)d_ws;
    float* H0            = (float*)ws;                               // 1 MB
    __hip_bfloat16* SP   = (__hip_bfloat16*)(ws + (1u << 20));       // 26.2 MB spike raster
    float* HR            = (float*)(ws + (1u << 20) + 26214400u);    // 52.4 MB drive raster
    char*  wbase         = ws + (1u << 20) + 26214400u + 52428800u;
    __hip_bfloat16* W1th = (__hip_bfloat16*)wbase;                   // 8.4 MB
    __hip_bfloat16* W1tl = W1th + (size_t)N2 * N1;                   // 8.4 MB
    __hip_bfloat16* W2th = W1tl + (size_t)N2 * N1;                   // 2.1 MB
    __hip_bfloat16* W2tl = W2th + (size_t)N3 * N2;                   // 2.1 MB

    // weight split+transpose (must run every call; ws is re-poisoned)
    split_transpose<<<dim3(N2 / 32, N1 / 32), 256, 0, stream>>>(W1, W1th, W1tl, N1, N2);
    split_transpose<<<dim3(N3 / 32, N2 / 32), 256, 0, stream>>>(W2, W2th, W2tl, N2, N3);

    // 1. H0 = inputs @ W0  (exact fp32)
    gemm_f32<<<dim3(N1 / 64, BATCH / 64), 256, 0, stream>>>(inputs, W0, H0, BATCH, N1, N0);

    // 2. layer-0 scan -> bf16 spike raster S0
    scan_l0<<<(BATCH * N1) / 256, 256, 0, stream>>>(H0, SP);

    // 3. H1 = S0 @ W1 via split-bf16 MFMA  (6400 x 2048 x 2048)
    gemm_bf16_split<128, 2, 2, 4, 4>
        <<<dim3(N2 / 128, (TSIM * BATCH) / 128), 256, 0, stream>>>(SP, W1th, W1tl, HR,
                                                                   TSIM * BATCH, N2, N1);

    // 4. layer-1 scan -> bf16 spike raster S1 (overwrites S0)
    scan_l1<<<(BATCH * N2) / 256, 256, 0, stream>>>(HR, SP);

    // 5. H2 = S1 @ W2 via split-bf16 MFMA  (6400 x 512 x 2048)
    gemm_bf16_split<64, 4, 1, 2, 4>
        <<<dim3(N3 / 64, (TSIM * BATCH) / 128), 256, 0, stream>>>(SP, W2th, W2tl, HR,
                                                                  TSIM * BATCH, N3, N2);

    // 6. layer-2 scan -> final membrane
    scan_l2<<<(BATCH * N3) / 256, 256, 0, stream>>>(HR, out);
}

// Round 3
// 236.672 us; speedup vs baseline: 4.9935x; 1.6259x over previous
//
#include <hip/hip_runtime.h>

#define ALPHA 0.9f
#define BETA  0.85f
#define TSIM  50
#define BATCH 128
#define N0    1024
#define N1    2048
#define N2    2048
#define N3    512

// ---------------------------------------------------------------------------
// Split-K fp32 tiled GEMM: Cp[z] = A(M,K-chunk z) @ B(chunk z, N).
// 64x64 tile, 256 threads, 4x4 micro-tile. M%64==0, N%64==0, KC%16==0.
// All three dense GEMMs here are M=128 (skinny) -> split-K for occupancy;
// consumers sum the z-partials.
// ---------------------------------------------------------------------------
__global__ __launch_bounds__(256) void gemm_f32_splitk(const float* __restrict__ A,
                                                       const float* __restrict__ B,
                                                       float* __restrict__ Cp,
                                                       int M, int N, int K, int KC) {
    __shared__ float As[16][65];
    __shared__ float Bs[16][68];

    const int tid = threadIdx.x;
    const int tx  = tid % 16;
    const int ty  = tid / 16;
    const int bx  = blockIdx.x;
    const int by  = blockIdx.y;
    const int z   = blockIdx.z;

    float acc[4][4] = {};

    const int ar = tid / 4;
    const int ak = (tid % 4) * 4;
    const int br = tid / 16;
    const int bc = (tid % 16) * 4;

    const int kbeg = z * KC;
    for (int k0 = kbeg; k0 < kbeg + KC; k0 += 16) {
        float4 av = *(const float4*)&A[(size_t)(by * 64 + ar) * K + k0 + ak];
        As[ak + 0][ar] = av.x;
        As[ak + 1][ar] = av.y;
        As[ak + 2][ar] = av.z;
        As[ak + 3][ar] = av.w;
        float4 bv = *(const float4*)&B[(size_t)(k0 + br) * N + bx * 64 + bc];
        *(float4*)&Bs[br][bc] = bv;
        __syncthreads();

#pragma unroll
        for (int kk = 0; kk < 16; ++kk) {
            float a0 = As[kk][ty * 4 + 0];
            float a1 = As[kk][ty * 4 + 1];
            float a2 = As[kk][ty * 4 + 2];
            float a3 = As[kk][ty * 4 + 3];
            float b0 = Bs[kk][tx * 4 + 0];
            float b1 = Bs[kk][tx * 4 + 1];
            float b2 = Bs[kk][tx * 4 + 2];
            float b3 = Bs[kk][tx * 4 + 3];
            acc[0][0] += a0 * b0; acc[0][1] += a0 * b1; acc[0][2] += a0 * b2; acc[0][3] += a0 * b3;
            acc[1][0] += a1 * b0; acc[1][1] += a1 * b1; acc[1][2] += a1 * b2; acc[1][3] += a1 * b3;
            acc[2][0] += a2 * b0; acc[2][1] += a2 * b1; acc[2][2] += a2 * b2; acc[2][3] += a2 * b3;
            acc[3][0] += a3 * b0; acc[3][1] += a3 * b1; acc[3][2] += a3 * b2; acc[3][3] += a3 * b3;
        }
        __syncthreads();
    }

#pragma unroll
    for (int i = 0; i < 4; ++i) {
        float4 v = make_float4(acc[i][0], acc[i][1], acc[i][2], acc[i][3]);
        *(float4*)&Cp[((size_t)z * M + by * 64 + ty * 4 + i) * N + bx * 64 + tx * 4] = v;
    }
}

// ---------------------------------------------------------------------------
// Layer-0: sum split-K partials -> h0; simulate the 50-step train (drive is
// t-constant); classify: constant train -> C0 in {0,1}; non-constant ->
// C0=0 + (j, 50-bit mask) entry. Deterministic per-b compaction (block scan)
// because downstream layers threshold on this data.
// One block per batch row b; 256 threads x 8 neurons.
// ---------------------------------------------------------------------------
__global__ __launch_bounds__(256) void scan_l0_classify(const float* __restrict__ P0,
                                                        float* __restrict__ C0,
                                                        int* __restrict__ jlist0,
                                                        unsigned long long* __restrict__ mask0,
                                                        int* __restrict__ count0) {
    const int b   = blockIdx.x;
    const int tid = threadIdx.x;
    __shared__ int cnt[256];

    int myj[8];
    unsigned long long mym[8];
    int mc = 0;
    const unsigned long long FULL = (1ull << TSIM) - 1ull;

#pragma unroll
    for (int i = 0; i < 8; ++i) {
        const int j = tid + i * 256;
        float h = 0.f;
#pragma unroll
        for (int zz = 0; zz < 4; ++zz) h += P0[((size_t)zz * BATCH + b) * N1 + j];
        float m = 0.f;
        unsigned long long mask = 0ull;
#pragma unroll
        for (int t = 0; t < TSIM; ++t) {
            m = BETA * m + h;                 // layer 0: s = h
            if (m - 1.f > 0.f) { mask |= (1ull << t); m = 0.f; }
        }
        float c = 0.f;
        if (mask == FULL) c = 1.f;
        else if (mask != 0ull) { myj[mc] = j; mym[mc] = mask; ++mc; }
        C0[(size_t)b * N1 + j] = c;
    }

    cnt[tid] = mc;
    __syncthreads();
    if (tid == 0) {
        int run = 0;
        for (int i = 0; i < 256; ++i) { int v = cnt[i]; cnt[i] = run; run += v; }
        count0[b] = run;
    }
    __syncthreads();
    const int off = cnt[tid];
    for (int i = 0; i < mc; ++i) {
        jlist0[(size_t)b * N1 + off + i] = myj[i];
        mask0[(size_t)b * N1 + off + i] = mym[i];
    }
}

// ---------------------------------------------------------------------------
// Layer-1 fused drive+scan: h1 train held in 50 registers =
// sum(PB1 partials) + sum over layer-0 residual entries of bit(t)*W1[j][jc].
// Then run the alpha/beta membrane scan in-place, classify the layer-1 spike
// train, emit C1 + residual entries (atomic append: order only perturbs
// layer-2 ROUNDING — no thresholds downstream — so non-determinism is safe).
// The 52 MB H1 raster is never materialized.
// Grid: (BATCH, N2/256); thread owns one (b, jc).
// ---------------------------------------------------------------------------
__global__ __launch_bounds__(256) void h1_scan(const float* __restrict__ PB1,
                                               const float* __restrict__ W1,
                                               const int* __restrict__ jlist0,
                                               const unsigned long long* __restrict__ mask0,
                                               const int* __restrict__ count0,
                                               float* __restrict__ C1,
                                               int* __restrict__ jlist1,
                                               unsigned long long* __restrict__ mask1,
                                               int* __restrict__ count1) {
    const int b  = blockIdx.x;
    const int jc = blockIdx.y * 256 + threadIdx.x;

    float base = 0.f;
#pragma unroll
    for (int z = 0; z < 8; ++z) base += PB1[((size_t)z * BATCH + b) * N2 + jc];

    float corr[TSIM];
#pragma unroll
    for (int t = 0; t < TSIM; ++t) corr[t] = 0.f;

    const int cnt = count0[b];
    for (int e = 0; e < cnt; ++e) {
        const int j               = jlist0[(size_t)b * N1 + e];
        const unsigned long long mk = mask0[(size_t)b * N1 + e];
        const float w             = W1[(size_t)j * N2 + jc];
        const unsigned lo = (unsigned)mk, hi = (unsigned)(mk >> 32);
#pragma unroll
        for (int t = 0; t < 32; ++t)
            if ((lo >> t) & 1u) corr[t] += w;
#pragma unroll
        for (int t = 32; t < TSIM; ++t)
            if ((hi >> (t - 32)) & 1u) corr[t] += w;
    }

    // membrane scan (layer 1: s = alpha*s + h; m = beta*m + s; reset on spike)
    float s = 0.f, m = 0.f;
    unsigned long long mask = 0ull;
#pragma unroll
    for (int t = 0; t < TSIM; ++t) {
        s = ALPHA * s + (base + corr[t]);
        m = BETA * m + s;
        if (m - 1.f > 0.f) { mask |= (1ull << t); m = 0.f; }
    }

    const unsigned long long FULL = (1ull << TSIM) - 1ull;
    float c = 0.f;
    if (mask == FULL) c = 1.f;
    else if (mask != 0ull) {
        const int off = atomicAdd(&count1[b], 1);
        jlist1[(size_t)b * N2 + off] = jc;
        mask1[(size_t)b * N2 + off] = mask;
    }
    C1[(size_t)b * N2 + jc] = c;
}

// ---------------------------------------------------------------------------
// Layer-2 fused drive+scan: h2 train in registers = sum(PB2) + residuals;
// output layer never resets; write final membrane directly to d_out.
// Grid: (BATCH, N3/256).
// ---------------------------------------------------------------------------
__global__ __launch_bounds__(256) void h2_scan(const float* __restrict__ PB2,
                                               const float* __restrict__ W2,
                                               const int* __restrict__ jlist1,
                                               const unsigned long long* __restrict__ mask1,
                                               const int* __restrict__ count1,
                                               float* __restrict__ out) {
    const int b  = blockIdx.x;
    const int jc = blockIdx.y * 256 + threadIdx.x;

    float base = 0.f;
#pragma unroll
    for (int z = 0; z < 8; ++z) base += PB2[((size_t)z * BATCH + b) * N3 + jc];

    float corr[TSIM];
#pragma unroll
    for (int t = 0; t < TSIM; ++t) corr[t] = 0.f;

    const int cnt = count1[b];
    for (int e = 0; e < cnt; ++e) {
        const int j               = jlist1[(size_t)b * N2 + e];
        const unsigned long long mk = mask1[(size_t)b * N2 + e];
        const float w             = W2[(size_t)j * N3 + jc];
        const unsigned lo = (unsigned)mk, hi = (unsigned)(mk >> 32);
#pragma unroll
        for (int t = 0; t < 32; ++t)
            if ((lo >> t) & 1u) corr[t] += w;
#pragma unroll
        for (int t = 32; t < TSIM; ++t)
            if ((hi >> (t - 32)) & 1u) corr[t] += w;
    }

    float s = 0.f, m = 0.f;
#pragma unroll
    for (int t = 0; t < TSIM; ++t) {
        s = ALPHA * s + (base + corr[t]);
        m = BETA * m + s;                     // no reset: output layer
    }
    out[(size_t)b * N3 + jc] = m;
}

extern "C" void kernel_launch(void* const* d_in, const int* in_sizes, int n_in,
                              void* d_out, int out_size, void* d_ws, size_t ws_size,
                              hipStream_t stream) {
    const float* inputs = (const float*)d_in[0];   // (128, 1024)
    const float* W0     = (const float*)d_in[1];   // (1024, 2048)
    const float* W1     = (const float*)d_in[2];   // (2048, 2048)
    const float* W2     = (const float*)d_in[3];   // (2048, 512)
    float* out = (float*)d_out;                    // (128, 512)

    // workspace layout (fp32 elements; ~22 MB total)
    float* P0  = (float*)d_ws;                     // 4 x 128 x 2048
    float* C0  = P0 + 4 * BATCH * N1;              // 128 x 2048
    float* PB1 = C0 + BATCH * N1;                  // 8 x 128 x 2048
    float* C1  = PB1 + 8 * BATCH * N2;             // 128 x 2048
    float* PB2 = C1 + BATCH * N2;                  // 8 x 128 x 512
    int* jl0   = (int*)(PB2 + 8 * BATCH * N3);     // 128 x 2048
    int* jl1   = jl0 + BATCH * N1;                 // 128 x 2048
    int* cnt0  = jl1 + BATCH * N2;                 // 128
    int* cnt1  = cnt0 + BATCH;                     // 128
    unsigned long long* mk0 = (unsigned long long*)(cnt1 + BATCH);  // 128 x 2048 (8B-aligned)
    unsigned long long* mk1 = mk0 + BATCH * N1;                     // 128 x 2048

    // zero the residual counters (ws is re-poisoned before every call)
    hipMemsetAsync(cnt0, 0, 2 * BATCH * sizeof(int), stream);

    // 1. P0[z] = inputs @ W0 chunks   (128 x 1024 x 2048, split-K 4)
    gemm_f32_splitk<<<dim3(N1 / 64, BATCH / 64, 4), 256, 0, stream>>>(
        inputs, W0, P0, BATCH, N1, N0, N0 / 4);

    // 2. layer-0 simulate + classify -> C0, residual list0
    scan_l0_classify<<<BATCH, 256, 0, stream>>>(P0, C0, jl0, mk0, cnt0);

    // 3. PB1[z] = C0 @ W1 chunks      (128 x 2048 x 2048, split-K 8)
    gemm_f32_splitk<<<dim3(N2 / 64, BATCH / 64, 8), 256, 0, stream>>>(
        C0, W1, PB1, BATCH, N2, N1, N1 / 8);

    // 4. fused layer-1 drive+scan+classify -> C1, residual list1
    h1_scan<<<dim3(BATCH, N2 / 256), 256, 0, stream>>>(
        PB1, W1, jl0, mk0, cnt0, C1, jl1, mk1, cnt1);

    // 5. PB2[z] = C1 @ W2 chunks      (128 x 2048 x 512, split-K 8)
    gemm_f32_splitk<<<dim3(N3 / 64, BATCH / 64, 8), 256, 0, stream>>>(
        C1, W2, PB2, BATCH, N3, N2, N2 / 8);

    // 6. fused layer-2 drive+scan -> final membrane directly to d_out
    h2_scan<<<dim3(BATCH, N3 / 256), 256, 0, stream>>>(
        PB2, W2, jl1, mk1, cnt1, out);
}

// Round 4
// 164.186 us; speedup vs baseline: 7.1981x; 1.4415x over previous
//
#include <hip/hip_runtime.h>

#define ALPHA 0.9f
#define BETA  0.85f
#define TSIM  50
#define BATCH 128
#define N0    1024
#define N1    2048
#define N2    2048
#define N3    512

// alpha^50, beta^50, 1/(alpha-beta)
#define A50   0.00515379f
#define B50   0.000295764f
#define INVAB 20.0f

// ---------------------------------------------------------------------------
// Split-K fp32 tiled GEMM: Cp[z] = A(M, K-chunk z) @ B(chunk z, N).
// 64x64 tile, 256 threads, 4x4 micro-tile. M%64==0, N%64==0, KC%16==0.
// All GEMMs here are M=128 (skinny) -> split-K for occupancy; consumers sum z.
// ---------------------------------------------------------------------------
__global__ __launch_bounds__(256) void gemm_f32_splitk(const float* __restrict__ A,
                                                       const float* __restrict__ B,
                                                       float* __restrict__ Cp,
                                                       int M, int N, int K, int KC) {
    __shared__ float As[16][65];
    __shared__ float Bs[16][68];

    const int tid = threadIdx.x;
    const int tx  = tid % 16;
    const int ty  = tid / 16;
    const int bx  = blockIdx.x;
    const int by  = blockIdx.y;
    const int z   = blockIdx.z;

    float acc[4][4] = {};

    const int ar = tid / 4;
    const int ak = (tid % 4) * 4;
    const int br = tid / 16;
    const int bc = (tid % 16) * 4;

    const int kbeg = z * KC;
    for (int k0 = kbeg; k0 < kbeg + KC; k0 += 16) {
        float4 av = *(const float4*)&A[(size_t)(by * 64 + ar) * K + k0 + ak];
        As[ak + 0][ar] = av.x;
        As[ak + 1][ar] = av.y;
        As[ak + 2][ar] = av.z;
        As[ak + 3][ar] = av.w;
        float4 bv = *(const float4*)&B[(size_t)(k0 + br) * N + bx * 64 + bc];
        *(float4*)&Bs[br][bc] = bv;
        __syncthreads();

#pragma unroll
        for (int kk = 0; kk < 16; ++kk) {
            float a0 = As[kk][ty * 4 + 0];
            float a1 = As[kk][ty * 4 + 1];
            float a2 = As[kk][ty * 4 + 2];
            float a3 = As[kk][ty * 4 + 3];
            float b0 = Bs[kk][tx * 4 + 0];
            float b1 = Bs[kk][tx * 4 + 1];
            float b2 = Bs[kk][tx * 4 + 2];
            float b3 = Bs[kk][tx * 4 + 3];
            acc[0][0] += a0 * b0; acc[0][1] += a0 * b1; acc[0][2] += a0 * b2; acc[0][3] += a0 * b3;
            acc[1][0] += a1 * b0; acc[1][1] += a1 * b1; acc[1][2] += a1 * b2; acc[1][3] += a1 * b3;
            acc[2][0] += a2 * b0; acc[2][1] += a2 * b1; acc[2][2] += a2 * b2; acc[2][3] += a2 * b3;
            acc[3][0] += a3 * b0; acc[3][1] += a3 * b1; acc[3][2] += a3 * b2; acc[3][3] += a3 * b3;
        }
        __syncthreads();
    }

#pragma unroll
    for (int i = 0; i < 4; ++i) {
        float4 v = make_float4(acc[i][0], acc[i][1], acc[i][2], acc[i][3]);
        *(float4*)&Cp[((size_t)z * M + by * 64 + ty * 4 + i) * N + bx * 64 + tx * 4] = v;
    }
}

// ---------------------------------------------------------------------------
// Layer-0 simulate + classify. Grid (BATCH, N1/256): block owns 256 neurons
// of one batch row. Sum 8 split-K partials -> h; 50-step scan (t-constant
// drive); constant trains -> C0 in {0,1}; time-varying -> residual entry
// (global j, 50-bit mask) in the per-(b,chunk) list, compacted
// deterministically via wave ballot + LDS wave-count scan.
// ---------------------------------------------------------------------------
__global__ __launch_bounds__(256) void scan_l0_classify(const float* __restrict__ P0,
                                                        float* __restrict__ C0,
                                                        int* __restrict__ jlist0,
                                                        unsigned long long* __restrict__ mask0,
                                                        int* __restrict__ count0) {
    const int b     = blockIdx.x;
    const int chunk = blockIdx.y;
    const int tid   = threadIdx.x;
    const int j     = chunk * 256 + tid;
    const int lane  = tid & 63;
    const int wv    = tid >> 6;

    float h = 0.f;
#pragma unroll
    for (int z = 0; z < 8; ++z) h += P0[((size_t)z * BATCH + b) * N1 + j];

    float m = 0.f;
    unsigned long long mask = 0ull;
#pragma unroll
    for (int t = 0; t < TSIM; ++t) {
        m = BETA * m + h;                   // layer 0: s = h
        if (m - 1.f > 0.f) { mask |= (1ull << t); m = 0.f; }
    }
    const unsigned long long FULL = (1ull << TSIM) - 1ull;
    C0[(size_t)b * N1 + j] = (mask == FULL) ? 1.f : 0.f;

    const bool has = (mask != 0ull) && (mask != FULL);
    const unsigned long long bal = __ballot(has);

    __shared__ int wcnt[4];
    if (lane == 0) wcnt[wv] = __popcll(bal);
    __syncthreads();
    int base = 0;
#pragma unroll
    for (int w = 0; w < 4; ++w)
        if (w < wv) base += wcnt[w];
    const int pos = base + __popcll(bal & ((1ull << lane) - 1ull));

    const size_t lbase = (size_t)(b * 8 + chunk) * 256;
    if (has) {
        jlist0[lbase + pos] = j;
        mask0[lbase + pos]  = mask;
    }
    if (tid == 0) count0[b * 8 + chunk] = wcnt[0] + wcnt[1] + wcnt[2] + wcnt[3];
}

// ---------------------------------------------------------------------------
// Layer-1 fused drive + membrane scan + LINEAR layer-2 projection.
// h1 train in 50 registers = sum(PB1 partials) + layer-0 residual corrections.
// During the scan, accumulate A2[b][j] = sum_t w_t * spike_t where
// w_t = (alpha^(50-t) - beta^(50-t))/(alpha-beta) — the exact linear weight of
// h2[t] in the (reset-free, threshold-free) output layer's final membrane.
// Then out = A2 @ W2 exactly. No residual lists, no atomics, no h2 raster.
// Grid: (BATCH, N2/256).
// ---------------------------------------------------------------------------
__global__ __launch_bounds__(256) void h1_scan_a2(const float* __restrict__ PB1,
                                                  const float* __restrict__ W1,
                                                  const int* __restrict__ jlist0,
                                                  const unsigned long long* __restrict__ mask0,
                                                  const int* __restrict__ count0,
                                                  float* __restrict__ A2) {
    const int b  = blockIdx.x;
    const int jc = blockIdx.y * 256 + threadIdx.x;

    float base = 0.f;
#pragma unroll
    for (int z = 0; z < 8; ++z) base += PB1[((size_t)z * BATCH + b) * N2 + jc];

    float corr[TSIM];
#pragma unroll
    for (int t = 0; t < TSIM; ++t) corr[t] = 0.f;

    for (int c = 0; c < 8; ++c) {
        const int cnt      = count0[b * 8 + c];
        const size_t lbase = (size_t)(b * 8 + c) * 256;
        for (int e = 0; e < cnt; ++e) {
            const int j                 = jlist0[lbase + e];
            const unsigned long long mk = mask0[lbase + e];
            const float w               = W1[(size_t)j * N2 + jc];
            const unsigned lo = (unsigned)mk, hi = (unsigned)(mk >> 32);
#pragma unroll
            for (int t = 0; t < 32; ++t)
                if ((lo >> t) & 1u) corr[t] += w;
#pragma unroll
            for (int t = 32; t < TSIM; ++t)
                if ((hi >> (t - 32)) & 1u) corr[t] += w;
        }
    }

    // membrane scan with folded w_t accumulation
    float s = 0.f, m = 0.f, a2 = 0.f;
    float pa = A50, pb = B50;                // alpha^(50-t), beta^(50-t) at t=0
    const float inva = 1.0f / ALPHA, invb = 1.0f / BETA;
#pragma unroll
    for (int t = 0; t < TSIM; ++t) {
        s = ALPHA * s + (base + corr[t]);
        m = BETA * m + s;
        if (m - 1.f > 0.f) {
            a2 += (pa - pb) * INVAB;         // += w_t
            m = 0.f;
        }
        pa *= inva;
        pb *= invb;
    }
    A2[(size_t)b * N2 + jc] = a2;
}

// ---------------------------------------------------------------------------
// Sum 16 split-K partials of A2@W2 -> final output (128 x 512).
// ---------------------------------------------------------------------------
__global__ __launch_bounds__(256) void reduce_out(const float* __restrict__ PB2,
                                                  float* __restrict__ out) {
    const int idx = blockIdx.x * 256 + threadIdx.x;   // over BATCH*N3
    float v = 0.f;
#pragma unroll
    for (int z = 0; z < 16; ++z) v += PB2[(size_t)z * (BATCH * N3) + idx];
    out[idx] = v;
}

extern "C" void kernel_launch(void* const* d_in, const int* in_sizes, int n_in,
                              void* d_out, int out_size, void* d_ws, size_t ws_size,
                              hipStream_t stream) {
    const float* inputs = (const float*)d_in[0];   // (128, 1024)
    const float* W0     = (const float*)d_in[1];   // (1024, 2048)
    const float* W1     = (const float*)d_in[2];   // (2048, 2048)
    const float* W2     = (const float*)d_in[3];   // (2048, 512)
    float* out = (float*)d_out;                    // (128, 512)

    // workspace layout (fp32 elements; ~25 MB total)
    float* P0  = (float*)d_ws;                     // 8 x 128 x 2048
    float* C0  = P0 + 8 * BATCH * N1;              // 128 x 2048
    float* PB1 = C0 + BATCH * N1;                  // 8 x 128 x 2048
    float* A2  = PB1 + 8 * BATCH * N2;             // 128 x 2048
    float* PB2 = A2 + BATCH * N2;                  // 16 x 128 x 512
    int* jl0   = (int*)(PB2 + 16 * BATCH * N3);    // 128 x 8 x 256
    int* cnt0  = jl0 + BATCH * N1;                 // 128 x 8
    unsigned long long* mk0 = (unsigned long long*)(cnt0 + 1024);  // 128 x 8 x 256

    // 1. P0[z] = inputs @ W0 chunks   (128 x 1024 x 2048, split-K 8)
    gemm_f32_splitk<<<dim3(N1 / 64, BATCH / 64, 8), 256, 0, stream>>>(
        inputs, W0, P0, BATCH, N1, N0, N0 / 8);

    // 2. layer-0 simulate + classify -> C0, residual lists (deterministic)
    scan_l0_classify<<<dim3(BATCH, N1 / 256), 256, 0, stream>>>(P0, C0, jl0, mk0, cnt0);

    // 3. PB1[z] = C0 @ W1 chunks      (128 x 2048 x 2048, split-K 8)
    gemm_f32_splitk<<<dim3(N2 / 64, BATCH / 64, 8), 256, 0, stream>>>(
        C0, W1, PB1, BATCH, N2, N1, N1 / 8);

    // 4. fused layer-1 drive + scan + linear layer-2 projection -> A2
    h1_scan_a2<<<dim3(BATCH, N2 / 256), 256, 0, stream>>>(
        PB1, W1, jl0, mk0, cnt0, A2);

    // 5. PB2[z] = A2 @ W2 chunks      (128 x 2048 x 512, split-K 16)
    gemm_f32_splitk<<<dim3(N3 / 64, BATCH / 64, 16), 256, 0, stream>>>(
        A2, W2, PB2, BATCH, N3, N2, N2 / 16);

    // 6. sum partials -> final membrane (128 x 512)
    reduce_out<<<(BATCH * N3) / 256, 256, 0, stream>>>(PB2, out);
}